// Round 7
// baseline (430.283 us; speedup 1.0000x reference)
//
#include <hip/hip_runtime.h>

#define VOCAB 512
#define EMB   128
#define HID   64
#define BATCH 256
#define TLEN  1024
#define CH    8               // steps per chunk
#define NCH   (TLEN / CH)     // 128 chunks
#define RS    64              // ring depth in steps
#define RCH   (RS / CH)       // 8 chunks per ring

typedef float v2f __attribute__((ext_vector_type(2)));

__device__ __forceinline__ float fast_tanh(float x) {
    // tanh(x) = 1 - 2/(exp(2x)+1); exact at both saturated ends.
    float e = __expf(2.0f * x);
    return 1.0f - 2.0f / (e + 1.0f);
}
__device__ __forceinline__ void lds_fence() {
    asm volatile("s_waitcnt lgkmcnt(0)" ::: "memory");
}
__device__ __forceinline__ void compiler_fence() {
    asm volatile("" ::: "memory");
}
__device__ __forceinline__ void nap() { __builtin_amdgcn_s_sleep(1); }

// ---- cross-lane primitives (addressless; no LDS banks involved) ----------
// ds_swizzle BitMode offsets: (xor<<10)|(or<<5)|and, and=0x1F
__device__ __forceinline__ float swz_xor4(float x) {
    return __int_as_float(__builtin_amdgcn_ds_swizzle(__float_as_int(x), 0x101F));
}
__device__ __forceinline__ float swz_xor8(float x) {
    return __int_as_float(__builtin_amdgcn_ds_swizzle(__float_as_int(x), 0x201F));
}
__device__ __forceinline__ float swz_xor16(float x) {
    return __int_as_float(__builtin_amdgcn_ds_swizzle(__float_as_int(x), 0x401F));
}
__device__ __forceinline__ float dpp_xor1(float x) {   // quad_perm [1,0,3,2]
    return __int_as_float(__builtin_amdgcn_update_dpp(
        0, __float_as_int(x), 0xB1, 0xF, 0xF, false));
}
__device__ __forceinline__ float dpp_xor2(float x) {   // quad_perm [2,3,0,1]
    return __int_as_float(__builtin_amdgcn_update_dpp(
        0, __float_as_int(x), 0x4E, 0xF, 0xF, false));
}
// lane^32 pair-sum: v_permlane32_swap (VALU; T12-verified on gfx950).
// swap(D=x,S=x): newD={x.row0, x.row0}… precisely newD.row1=S.row0,
// newS.row0=D.row1 -> for every lane newD+newS = x(L) + x(L^32).
__device__ __forceinline__ float xor32_sum(float x) {
#if __has_builtin(__builtin_amdgcn_permlane32_swap)
    auto r = __builtin_amdgcn_permlane32_swap(
        __float_as_int(x), __float_as_int(x), false, false);
    return __int_as_float(r[0]) + __int_as_float(r[1]);
#else
    return x + __shfl_xor(x, 32);
#endif
}
// full sum across the 4 lanes {L, L^16, L^32, L^48}
__device__ __forceinline__ float reduce4(float z) {
    float s = xor32_sum(z);
    return s + swz_xor16(s);
}
// XOR-butterfly all-gather within the contiguous 16-lane row:
// sv[m] = v at lane (L & 48) | ((L & 15) ^ m).   3 swizzle + 12 DPP.
__device__ __forceinline__ void gather16(float v, float (&sv)[16]) {
    float g4  = swz_xor4(v);
    float g8  = swz_xor8(v);
    float g12 = swz_xor8(g4);
    sv[0] = v;   sv[4] = g4;   sv[8] = g8;   sv[12] = g12;
    sv[2]  = dpp_xor2(v);   sv[6]  = dpp_xor2(g4);
    sv[10] = dpp_xor2(g8);  sv[14] = dpp_xor2(g12);
    sv[1]  = dpp_xor1(sv[0]);   sv[3]  = dpp_xor1(sv[2]);
    sv[5]  = dpp_xor1(sv[4]);   sv[7]  = dpp_xor1(sv[6]);
    sv[9]  = dpp_xor1(sv[8]);   sv[11] = dpp_xor1(sv[10]);
    sv[13] = dpp_xor1(sv[12]);  sv[15] = dpp_xor1(sv[14]);
}
// 4-row partial dot: z[j] = sum_t sv[t] * w[j][t]  (t-order matches pack)
__device__ __forceinline__ void dot4(const float (&sv)[16],
                                     const v2f (&w)[4][8], float (&z)[4]) {
    #pragma unroll
    for (int j = 0; j < 4; ++j) {
        v2f a0 = v2f{0.f, 0.f}, a1 = v2f{0.f, 0.f};
        #pragma unroll
        for (int u = 0; u < 4; ++u) {
            a0 = __builtin_elementwise_fma(v2f{sv[4*u],   sv[4*u+1]}, w[j][2*u],   a0);
            a1 = __builtin_elementwise_fma(v2f{sv[4*u+2], sv[4*u+3]}, w[j][2*u+1], a1);
        }
        v2f s = a0 + a1;
        z[j] = s.x + s.y;
    }
}
// weight packs (init-only scalar loads). bfly: col(t) = 4*(pos^t)+c to match
// gather16's absolute XOR indexing. plain: col(t) = 4*t+c for ring-fed dots.
__device__ __forceinline__ void load_w_bfly(v2f (&w)[4][8],
                                            const float* __restrict__ W,
                                            int pos, int c) {
    #pragma unroll
    for (int j = 0; j < 4; ++j) {
        const float* wr = W + (4 * pos + j) * HID;
        #pragma unroll
        for (int u = 0; u < 8; ++u)
            w[j][u] = v2f{wr[4 * (pos ^ (2*u))     + c],
                          wr[4 * (pos ^ (2*u + 1)) + c]};
    }
}
__device__ __forceinline__ void load_w_plain(v2f (&w)[4][8],
                                             const float* __restrict__ W,
                                             int pos, int c) {
    #pragma unroll
    for (int j = 0; j < 4; ++j) {
        const float* wr = W + (4 * pos + j) * HID;
        #pragma unroll
        for (int u = 0; u < 8; ++u)
            w[j][u] = v2f{wr[4 * (2*u)     + c],
                          wr[4 * (2*u + 1) + c]};
    }
}

// ---------------------------------------------------------------------------
// Kernel 1: P0[v][i] = sum_e emb[v][e]*Wih0[i][e] + bih0[i] + bhh0[i]  (fp32)
// ---------------------------------------------------------------------------
__global__ void __launch_bounds__(64) p0_kernel(
    const float* __restrict__ emb,
    const float* __restrict__ wih0,
    const float* __restrict__ bih0,
    const float* __restrict__ bhh0,
    float* __restrict__ P0)
{
    const int v = blockIdx.x;
    const int i = threadIdx.x;
    const float4* er = (const float4*)(emb  + v * EMB);
    const float4* wr = (const float4*)(wih0 + i * EMB);
    float a0 = 0.f, a1 = 0.f, a2 = 0.f, a3 = 0.f;
    #pragma unroll
    for (int k = 0; k < EMB / 4; ++k) {
        float4 e4 = er[k];
        float4 w4 = wr[k];
        a0 = fmaf(e4.x, w4.x, a0);
        a1 = fmaf(e4.y, w4.y, a1);
        a2 = fmaf(e4.z, w4.z, a2);
        a3 = fmaf(e4.w, w4.w, a3);
    }
    P0[v * HID + i] = (a0 + a1) + (a2 + a3) + bih0[i] + bhh0[i];
}

// ---------------------------------------------------------------------------
// Kernel 2 (R14): register-resident recurrence. R13 post-mortem: 440 of 583
// cyc/step was the ds_write->ds_read_b128 RTT. Here the recurrent broadcast
// is a DPP/swizzle exchange network (reduce: permlane32+swz16; all-gather:
// swz8/swz4 + 12 quad_perm) -- NO round-trip. LDS only for inter-wave
// handoff (lane-linear writes, contiguous b128 reads, all <=2-way aliases).
// Lane map: c=lane>>4 (k-residue), pos=lane&15 (rows 4pos..4pos+3).
//   wave0: h0[t] = tanh(P0[x[t]] + Whh0 h0[t-1])   -> h0ring[slot][lane]
//   wave1: p[t]  = b1 + Wih1 h0[t]  (ring-fed)     -> p1ring[slot][row]
//   wave2: h1[t] = tanh(p[t] + Whh1 h1[t-1]); MLP head at the end.
// ---------------------------------------------------------------------------
__global__ void __launch_bounds__(192, 1) rnn_kernel(
    const int*   __restrict__ xs,
    const float* __restrict__ P0,
    const float* __restrict__ Whh0,
    const float* __restrict__ Wih1,
    const float* __restrict__ Whh1,
    const float* __restrict__ bih1,
    const float* __restrict__ bhh1,
    const float* __restrict__ W1,
    const float* __restrict__ b1,
    const float* __restrict__ W2,
    const float* __restrict__ b2,
    float*       __restrict__ out)
{
    __shared__ float h0ring[RS][HID];   // 16 KiB; pos-major: [16c+pos]=h[4pos+c]
    __shared__ float p1ring[RS][HID];   // 16 KiB; plain: [r]=p[r]
    __shared__ float h1fin[HID];
    __shared__ int   flags[3];

    const int b    = blockIdx.x;
    const int tid  = threadIdx.x;
    const int wv   = tid >> 6;
    const int lane = tid & 63;
    const int pos  = lane & 15;
    const int c    = lane >> 4;
    const bool c1  = (c & 1) != 0;
    const bool c2  = (c & 2) != 0;

    const int* xrow = xs + b * TLEN;
    // vz == 0, but opaque to uniformity analysis -> forces VECTOR loads
    // (vmcnt path) for the x reads instead of s_load (lgkmcnt path).
    const int vz = (int)__builtin_amdgcn_mbcnt_lo(0u, 0u);

    if (tid < 3) flags[tid] = 0;
    __syncthreads();                     // the ONLY barrier in the kernel

    volatile int* vf = (volatile int*)flags;

    if (wv == 0) {
        // ================= wave0: layer-0 recurrence ======================
        v2f w0[4][8];
        load_w_bfly(w0, Whh0, pos, c);

        int    xv_old[CH];
        float4 a_old[CH];                // P0[x][4pos..4pos+3] per step
        #pragma unroll
        for (int i = 0; i < CH; ++i)
            xv_old[i] = xrow[CH + i + vz] & (VOCAB - 1);
        #pragma unroll
        for (int i = 0; i < CH; ++i)
            a_old[i] = *(const float4*)(P0 + (xrow[i + vz] & (VOCAB - 1)) * HID + 4 * pos);

        float sv[16];
        #pragma unroll
        for (int m = 0; m < 16; ++m) sv[m] = 0.f;   // h0[-1] = 0

        #pragma unroll 1
        for (int k = 0; k < NCH; ++k) {
            if (k >= RCH) {              // h0ring slot-reuse guard (wave1)
                while (vf[1] < k - (RCH - 1)) nap();
                compiler_fence();
            }
            const int  cc2 = (k + 2 < NCH) ? (k + 2) : (NCH - 1);
            const int* xp  = xrow + cc2 * CH;
            int    xv_new[CH];
            float4 a_new[CH];
            #pragma unroll
            for (int i = 0; i < CH; ++i)
                xv_new[i] = xp[i + vz] & (VOCAB - 1);
            #pragma unroll
            for (int i = 0; i < CH; ++i)
                a_new[i] = *(const float4*)(P0 + xv_old[i] * HID + 4 * pos);

            const int base = (k & (RCH - 1)) * CH;
            #pragma unroll
            for (int i = 0; i < CH; ++i) {
                float z[4];
                dot4(sv, w0, z);
                float4 a = a_old[i];
                float h0v = fast_tanh(reduce4(z[0]) + a.x);
                float h1v = fast_tanh(reduce4(z[1]) + a.y);
                float h2v = fast_tanh(reduce4(z[2]) + a.z);
                float h3v = fast_tanh(reduce4(z[3]) + a.w);
                float v = c1 ? (c2 ? h3v : h1v) : (c2 ? h2v : h0v); // hq[c]
                h0ring[base + i][lane] = v;      // fire-and-forget handoff
                gather16(v, sv);                 // in-register re-broadcast
            }
            lds_fence();
            if (lane == 0) vf[0] = k + 1;

            #pragma unroll
            for (int i = 0; i < CH; ++i) { a_old[i] = a_new[i]; xv_old[i] = xv_new[i]; }
        }
    } else if (wv == 1) {
        // ================= wave1: p1 projection (no recurrence) ===========
        v2f wp[4][8];
        load_w_plain(wp, Wih1, pos, c);
        float4 b4;
        b4.x = bih1[4 * pos + 0] + bhh1[4 * pos + 0];
        b4.y = bih1[4 * pos + 1] + bhh1[4 * pos + 1];
        b4.z = bih1[4 * pos + 2] + bhh1[4 * pos + 2];
        b4.w = bih1[4 * pos + 3] + bhh1[4 * pos + 3];

        #pragma unroll 1
        for (int k = 0; k < NCH; ++k) {
            while (vf[0] < k + 1) nap();
            if (k >= RCH) { while (vf[2] < k - (RCH - 1)) nap(); }
            compiler_fence();
            const int base = (k & (RCH - 1)) * CH;
            #pragma unroll
            for (int i = 0; i < CH; ++i) {
                const float* hr = &h0ring[base + i][16 * c];
                float4 q0 = *(const float4*)(hr + 0);
                float4 q1 = *(const float4*)(hr + 4);
                float4 q2 = *(const float4*)(hr + 8);
                float4 q3 = *(const float4*)(hr + 12);
                float hsg[16] = {q0.x, q0.y, q0.z, q0.w, q1.x, q1.y, q1.z, q1.w,
                                 q2.x, q2.y, q2.z, q2.w, q3.x, q3.y, q3.z, q3.w};
                float z[4];
                dot4(hsg, wp, z);
                float4 pout;
                pout.x = reduce4(z[0]) + b4.x;
                pout.y = reduce4(z[1]) + b4.y;
                pout.z = reduce4(z[2]) + b4.z;
                pout.w = reduce4(z[3]) + b4.w;
                if (c == 0) *(float4*)&p1ring[base + i][4 * pos] = pout;
            }
            lds_fence();
            if (lane == 0) vf[1] = k + 1;
        }
    } else {
        // ================= wave2: layer-1 recurrence + MLP head ===========
        v2f w2[4][8];
        load_w_bfly(w2, Whh1, pos, c);

        float sv[16];
        #pragma unroll
        for (int m = 0; m < 16; ++m) sv[m] = 0.f;   // h1[-1] = 0
        float hq0 = 0.f, hq1 = 0.f, hq2 = 0.f, hq3 = 0.f;

        #pragma unroll 1
        for (int k = 0; k < NCH; ++k) {
            while (vf[1] < k + 1) nap();
            compiler_fence();
            const int base = (k & (RCH - 1)) * CH;
            float4 p4[CH];               // bulk p prefetch (b128, 2-way free)
            #pragma unroll
            for (int i = 0; i < CH; ++i)
                p4[i] = *(const float4*)&p1ring[base + i][4 * pos];
            #pragma unroll
            for (int i = 0; i < CH; ++i) {
                float z[4];
                dot4(sv, w2, z);
                hq0 = fast_tanh(reduce4(z[0]) + p4[i].x);
                hq1 = fast_tanh(reduce4(z[1]) + p4[i].y);
                hq2 = fast_tanh(reduce4(z[2]) + p4[i].z);
                hq3 = fast_tanh(reduce4(z[3]) + p4[i].w);
                float v = c1 ? (c2 ? hq3 : hq1) : (c2 ? hq2 : hq0);
                gather16(v, sv);         // no LDS write: purely in-register
            }
            lds_fence();                 // p reads of this chunk consumed
            if (lane == 0) vf[2] = k + 1;
        }
        // ---- MLP head: y = relu(h1 @ W1^T + b1) @ W2^T + b2 ----
        if (c == 0) *(float4*)&h1fin[4 * pos] = float4{hq0, hq1, hq2, hq3};
        lds_fence();
        float r = 0.f;
        if (lane < 32) {
            float acc = b1[lane];
            const float* w1row = W1 + lane * HID;
            #pragma unroll
            for (int j = 0; j < HID; ++j) acc = fmaf(w1row[j], h1fin[j], acc);
            r = fmaxf(acc, 0.f) * W2[lane];
        }
        #pragma unroll
        for (int off = 32; off > 0; off >>= 1) r += __shfl_down(r, off);
        if (lane == 0) out[b] = r + b2[0];
    }
}

extern "C" void kernel_launch(void* const* d_in, const int* in_sizes, int n_in,
                              void* d_out, int out_size, void* d_ws, size_t ws_size,
                              hipStream_t stream)
{
    const int*   x    = (const int*)d_in[0];
    const float* emb  = (const float*)d_in[1];
    const float* Wih0 = (const float*)d_in[2];
    const float* Whh0 = (const float*)d_in[3];
    const float* bih0 = (const float*)d_in[4];
    const float* bhh0 = (const float*)d_in[5];
    const float* Wih1 = (const float*)d_in[6];
    const float* Whh1 = (const float*)d_in[7];
    const float* bih1 = (const float*)d_in[8];
    const float* bhh1 = (const float*)d_in[9];
    const float* W1   = (const float*)d_in[10];
    const float* b1   = (const float*)d_in[11];
    const float* W2   = (const float*)d_in[12];
    const float* b2   = (const float*)d_in[13];

    float* P0 = (float*)d_ws;   // 512*64*4 = 128 KiB scratch

    hipLaunchKernelGGL(p0_kernel, dim3(VOCAB), dim3(HID), 0, stream,
                       emb, Wih0, bih0, bhh0, P0);
    hipLaunchKernelGGL(rnn_kernel, dim3(BATCH), dim3(192), 0, stream,
                       x, P0, Whh0, Wih1, Whh1, bih1, bhh1,
                       W1, b1, W2, b2, (float*)d_out);
}

// Round 8
// 382.418 us; speedup vs baseline: 1.1252x; 1.1252x over previous
//
#include <hip/hip_runtime.h>

#define VOCAB 512
#define EMB   128
#define HID   64
#define BATCH 256
#define TLEN  1024
#define CH    8               // steps per chunk
#define NCH   (TLEN / CH)     // 128 chunks
#define RS    64              // ring depth in steps
#define RCH   (RS / CH)       // 8 chunks per ring

typedef float v2f __attribute__((ext_vector_type(2)));

__device__ __forceinline__ float fast_tanh(float x) {
    // tanh(x) = 1 - 2/(exp(2x)+1); exact at both saturated ends.
    float e = __expf(2.0f * x);
    return 1.0f - 2.0f / (e + 1.0f);
}
__device__ __forceinline__ void lds_fence() {
    asm volatile("s_waitcnt lgkmcnt(0)" ::: "memory");
}
__device__ __forceinline__ void compiler_fence() {
    asm volatile("" ::: "memory");
}
__device__ __forceinline__ void nap() { __builtin_amdgcn_s_sleep(1); }

// ---- cross-lane primitives --------------------------------------------
// R14 post-mortem: ds_swizzle is a DS-pipe op with LDS-class latency; it
// poisoned the recurrent chain. R15: every exchange below is PURE VALU.
__device__ __forceinline__ float swz_xor16(float x) {   // fallback only
    return __int_as_float(__builtin_amdgcn_ds_swizzle(__float_as_int(x), 0x401F));
}
__device__ __forceinline__ float dpp_xor1(float x) {    // quad_perm [1,0,3,2]
    return __int_as_float(__builtin_amdgcn_update_dpp(
        0, __float_as_int(x), 0xB1, 0xF, 0xF, false));
}
__device__ __forceinline__ float dpp_xor2(float x) {    // quad_perm [2,3,0,1]
    return __int_as_float(__builtin_amdgcn_update_dpp(
        0, __float_as_int(x), 0x4E, 0xF, 0xF, false));
}
__device__ __forceinline__ float dpp_hm(float x) {      // row_half_mirror = ^7
    return __int_as_float(__builtin_amdgcn_update_dpp(
        0, __float_as_int(x), 0x141, 0xF, 0xF, false));
}
__device__ __forceinline__ float dpp_ror8(float x) {    // row_ror:8 = ^8 (16-row)
    return __int_as_float(__builtin_amdgcn_update_dpp(
        0, __float_as_int(x), 0x128, 0xF, 0xF, false));
}
__device__ __forceinline__ float dpp_xor4(float x) {    // ^7 then ^2 then ^1 = ^4
    return dpp_xor1(dpp_xor2(dpp_hm(x)));
}
// lane^32 pair-sum via v_permlane32_swap (VALU; R14-proven, absmax 0).
__device__ __forceinline__ float xor32_sum(float x) {
#if __has_builtin(__builtin_amdgcn_permlane32_swap)
    auto r = __builtin_amdgcn_permlane32_swap(
        __float_as_int(x), __float_as_int(x), false, false);
    return __int_as_float(r[0]) + __int_as_float(r[1]);
#else
    return x + __shfl_xor(x, 32);
#endif
}
// lane^16 pair-sum via v_permlane16_swap (VALU): swaps odd 16-rows of D
// with even 16-rows of S; with D=S=x, newD+newS = x(L)+x(L^16) (same
// algebra as the proven permlane32 trick). Fallback: proven ds_swizzle.
__device__ __forceinline__ float xor16_sum(float x) {
#if __has_builtin(__builtin_amdgcn_permlane16_swap)
    auto r = __builtin_amdgcn_permlane16_swap(
        __float_as_int(x), __float_as_int(x), false, false);
    return __int_as_float(r[0]) + __int_as_float(r[1]);
#else
    return x + swz_xor16(x);
#endif
}
// full sum across lanes {L, L^16, L^32, L^48} -- zero DS ops
__device__ __forceinline__ float reduce4(float z) {
    return xor16_sum(xor32_sum(z));
}
// XOR-butterfly all-gather within the contiguous 16-lane row (R14-proven
// mapping, DS-free internals): sv[d] = v at lane (L&48)|((L&15)^d).
__device__ __forceinline__ void gather16(float v, float (&sv)[16]) {
    float g4  = dpp_xor4(v);
    float g8  = dpp_ror8(v);
    float g12 = dpp_ror8(g4);
    sv[0] = v;   sv[4] = g4;   sv[8] = g8;   sv[12] = g12;
    sv[2]  = dpp_xor2(v);   sv[6]  = dpp_xor2(g4);
    sv[10] = dpp_xor2(g8);  sv[14] = dpp_xor2(g12);
    sv[1]  = dpp_xor1(sv[0]);   sv[3]  = dpp_xor1(sv[2]);
    sv[5]  = dpp_xor1(sv[4]);   sv[7]  = dpp_xor1(sv[6]);
    sv[9]  = dpp_xor1(sv[8]);   sv[11] = dpp_xor1(sv[10]);
    sv[13] = dpp_xor1(sv[12]);  sv[15] = dpp_xor1(sv[14]);
}
// 4-row partial dot: z[j] = sum_t sv[t] * w[j][t]  (R14-proven)
__device__ __forceinline__ void dot4(const float (&sv)[16],
                                     const v2f (&w)[4][8], float (&z)[4]) {
    #pragma unroll
    for (int j = 0; j < 4; ++j) {
        v2f a0 = v2f{0.f, 0.f}, a1 = v2f{0.f, 0.f};
        #pragma unroll
        for (int u = 0; u < 4; ++u) {
            a0 = __builtin_elementwise_fma(v2f{sv[4*u],   sv[4*u+1]}, w[j][2*u],   a0);
            a1 = __builtin_elementwise_fma(v2f{sv[4*u+2], sv[4*u+3]}, w[j][2*u+1], a1);
        }
        v2f s = a0 + a1;
        z[j] = s.x + s.y;
    }
}
// weight packs (init-only). bfly: col(t)=4*(pos^t)+c matches gather16's
// XOR indexing (R14-proven). plain: col(t)=4*t+c for ring-fed dots.
__device__ __forceinline__ void load_w_bfly(v2f (&w)[4][8],
                                            const float* __restrict__ W,
                                            int pos, int c) {
    #pragma unroll
    for (int j = 0; j < 4; ++j) {
        const float* wr = W + (4 * pos + j) * HID;
        #pragma unroll
        for (int u = 0; u < 8; ++u)
            w[j][u] = v2f{wr[4 * (pos ^ (2*u))     + c],
                          wr[4 * (pos ^ (2*u + 1)) + c]};
    }
}
__device__ __forceinline__ void load_w_plain(v2f (&w)[4][8],
                                             const float* __restrict__ W,
                                             int pos, int c) {
    #pragma unroll
    for (int j = 0; j < 4; ++j) {
        const float* wr = W + (4 * pos + j) * HID;
        #pragma unroll
        for (int u = 0; u < 8; ++u)
            w[j][u] = v2f{wr[4 * (2*u)     + c],
                          wr[4 * (2*u + 1) + c]};
    }
}

// ---------------------------------------------------------------------------
// Kernel 1: P0[v][i] = sum_e emb[v][e]*Wih0[i][e] + bih0[i] + bhh0[i]  (fp32)
// ---------------------------------------------------------------------------
__global__ void __launch_bounds__(64) p0_kernel(
    const float* __restrict__ emb,
    const float* __restrict__ wih0,
    const float* __restrict__ bih0,
    const float* __restrict__ bhh0,
    float* __restrict__ P0)
{
    const int v = blockIdx.x;
    const int i = threadIdx.x;
    const float4* er = (const float4*)(emb  + v * EMB);
    const float4* wr = (const float4*)(wih0 + i * EMB);
    float a0 = 0.f, a1 = 0.f, a2 = 0.f, a3 = 0.f;
    #pragma unroll
    for (int k = 0; k < EMB / 4; ++k) {
        float4 e4 = er[k];
        float4 w4 = wr[k];
        a0 = fmaf(e4.x, w4.x, a0);
        a1 = fmaf(e4.y, w4.y, a1);
        a2 = fmaf(e4.z, w4.z, a2);
        a3 = fmaf(e4.w, w4.w, a3);
    }
    P0[v * HID + i] = (a0 + a1) + (a2 + a3) + bih0[i] + bhh0[i];
}

// ---------------------------------------------------------------------------
// Kernel 2 (R15): 3-wave pipeline, ALL-VALU recurrent chains.
// R14 lesson: ds_swizzle has DS latency -> recurrence chain must be pure
// VALU. reduce4 = permlane32+permlane16 pair-sums; gather16 = 19 DPPs.
// Recurrent waves touch LDS once per step (1 fire-and-forget b32 write).
//   wave0: h0[t] = tanh(P0[x[t]] + Whh0 h0[t-1])   -> h0ring[slot][lane]
//   wave1: p[t]  = b1 + Wih1 h0[t]  (ring-fed, next-seg prefetch)
//   wave2: h1[t] = tanh(p[t] + Whh1 h1[t-1]); MLP head at the end.
// Lane map (R14-proven): c=lane>>4 (k-residue), pos=lane&15 (rows 4pos+j).
// ---------------------------------------------------------------------------
__global__ void __launch_bounds__(192, 1) rnn_kernel(
    const int*   __restrict__ xs,
    const float* __restrict__ P0,
    const float* __restrict__ Whh0,
    const float* __restrict__ Wih1,
    const float* __restrict__ Whh1,
    const float* __restrict__ bih1,
    const float* __restrict__ bhh1,
    const float* __restrict__ W1,
    const float* __restrict__ b1,
    const float* __restrict__ W2,
    const float* __restrict__ b2,
    float*       __restrict__ out)
{
    __shared__ float h0ring[RS][HID];   // 16 KiB; [16c+pos] = h[4pos+c]
    __shared__ float p1ring[RS][HID];   // 16 KiB; plain: [r] = p[r]
    __shared__ float h1fin[HID];
    __shared__ int   flags[3];

    const int b    = blockIdx.x;
    const int tid  = threadIdx.x;
    const int wv   = tid >> 6;
    const int lane = tid & 63;
    const int pos  = lane & 15;
    const int c    = lane >> 4;
    const bool c1  = (c & 1) != 0;
    const bool c2  = (c & 2) != 0;

    const int* xrow = xs + b * TLEN;
    // vz == 0, but opaque to uniformity analysis -> forces VECTOR loads
    // (vmcnt path) for the x reads instead of s_load (lgkmcnt path).
    const int vz = (int)__builtin_amdgcn_mbcnt_lo(0u, 0u);

    if (tid < 3) flags[tid] = 0;
    __syncthreads();                     // the ONLY barrier in the kernel

    volatile int* vf = (volatile int*)flags;

    if (wv == 0) {
        // ================= wave0: layer-0 recurrence ======================
        v2f w0[4][8];
        load_w_bfly(w0, Whh0, pos, c);

        int    xv_old[CH];
        float4 a_old[CH];                // P0[x][4pos..4pos+3] per step
        #pragma unroll
        for (int i = 0; i < CH; ++i)
            xv_old[i] = xrow[CH + i + vz] & (VOCAB - 1);
        #pragma unroll
        for (int i = 0; i < CH; ++i)
            a_old[i] = *(const float4*)(P0 + (xrow[i + vz] & (VOCAB - 1)) * HID + 4 * pos);

        float sv[16];
        #pragma unroll
        for (int m = 0; m < 16; ++m) sv[m] = 0.f;   // h0[-1] = 0

        #pragma unroll 1
        for (int k = 0; k < NCH; ++k) {
            if (k >= RCH) {              // h0ring slot-reuse guard (wave1)
                while (vf[1] < k - (RCH - 1)) nap();
                compiler_fence();
            }
            const int  cc2 = (k + 2 < NCH) ? (k + 2) : (NCH - 1);
            const int* xp  = xrow + cc2 * CH;
            int    xv_new[CH];
            float4 a_new[CH];
            #pragma unroll
            for (int i = 0; i < CH; ++i)
                xv_new[i] = xp[i + vz] & (VOCAB - 1);
            #pragma unroll
            for (int i = 0; i < CH; ++i)
                a_new[i] = *(const float4*)(P0 + xv_old[i] * HID + 4 * pos);

            const int base = (k & (RCH - 1)) * CH;
            #pragma unroll
            for (int i = 0; i < CH; ++i) {
                float z[4];
                dot4(sv, w0, z);
                float4 a = a_old[i];
                float zf0 = reduce4(z[0]) + a.x;
                float zf1 = reduce4(z[1]) + a.y;
                float zf2 = reduce4(z[2]) + a.z;
                float zf3 = reduce4(z[3]) + a.w;
                // select row pos*4+c FIRST, then one tanh (was 4 in R14)
                float zs = c1 ? (c2 ? zf3 : zf1) : (c2 ? zf2 : zf0);
                float v  = fast_tanh(zs);
                h0ring[base + i][lane] = v;      // fire-and-forget handoff
                gather16(v, sv);                 // pure-VALU re-broadcast
            }
            lds_fence();
            if (lane == 0) vf[0] = k + 1;

            #pragma unroll
            for (int i = 0; i < CH; ++i) { a_old[i] = a_new[i]; xv_old[i] = xv_new[i]; }
        }
    } else if (wv == 1) {
        // ================= wave1: p1 projection (no recurrence) ===========
        v2f wp[4][8];
        load_w_plain(wp, Wih1, pos, c);
        float4 b4;
        b4.x = bih1[4 * pos + 0] + bhh1[4 * pos + 0];
        b4.y = bih1[4 * pos + 1] + bhh1[4 * pos + 1];
        b4.z = bih1[4 * pos + 2] + bhh1[4 * pos + 2];
        b4.w = bih1[4 * pos + 3] + bhh1[4 * pos + 3];

        #pragma unroll 1
        for (int k = 0; k < NCH; ++k) {
            while (vf[0] < k + 1) nap();
            if (k >= RCH) { while (vf[2] < k - (RCH - 1)) nap(); }
            compiler_fence();
            const int base = (k & (RCH - 1)) * CH;
            float4 c0[4];                // seg for current step (prefetched)
            {
                const float4* hr = (const float4*)&h0ring[base][16 * c];
                c0[0] = hr[0]; c0[1] = hr[1]; c0[2] = hr[2]; c0[3] = hr[3];
            }
            #pragma unroll
            for (int i = 0; i < CH; ++i) {
                float4 nx[4];
                if (i < CH - 1) {        // next-step seg read hides under dot
                    const float4* hr = (const float4*)&h0ring[base + i + 1][16 * c];
                    nx[0] = hr[0]; nx[1] = hr[1]; nx[2] = hr[2]; nx[3] = hr[3];
                }
                float hsg[16] = {c0[0].x, c0[0].y, c0[0].z, c0[0].w,
                                 c0[1].x, c0[1].y, c0[1].z, c0[1].w,
                                 c0[2].x, c0[2].y, c0[2].z, c0[2].w,
                                 c0[3].x, c0[3].y, c0[3].z, c0[3].w};
                float z[4];
                dot4(hsg, wp, z);
                float4 pout;
                pout.x = reduce4(z[0]) + b4.x;
                pout.y = reduce4(z[1]) + b4.y;
                pout.z = reduce4(z[2]) + b4.z;
                pout.w = reduce4(z[3]) + b4.w;
                if (c == 0) *(float4*)&p1ring[base + i][4 * pos] = pout;
                if (i < CH - 1) {
                    #pragma unroll
                    for (int q = 0; q < 4; ++q) c0[q] = nx[q];
                }
            }
            lds_fence();
            if (lane == 0) vf[1] = k + 1;
        }
    } else {
        // ================= wave2: layer-1 recurrence + MLP head ===========
        v2f w2[4][8];
        load_w_bfly(w2, Whh1, pos, c);

        float sv[16];
        #pragma unroll
        for (int m = 0; m < 16; ++m) sv[m] = 0.f;   // h1[-1] = 0
        float zl0 = 0.f, zl1 = 0.f, zl2 = 0.f, zl3 = 0.f;  // last pre-tanh z

        #pragma unroll 1
        for (int k = 0; k < NCH; ++k) {
            while (vf[1] < k + 1) nap();
            compiler_fence();
            const int base = (k & (RCH - 1)) * CH;
            float4 p4[CH];               // bulk p prefetch (b128, 2-way free)
            #pragma unroll
            for (int i = 0; i < CH; ++i)
                p4[i] = *(const float4*)&p1ring[base + i][4 * pos];
            #pragma unroll
            for (int i = 0; i < CH; ++i) {
                float z[4];
                dot4(sv, w2, z);
                zl0 = reduce4(z[0]) + p4[i].x;
                zl1 = reduce4(z[1]) + p4[i].y;
                zl2 = reduce4(z[2]) + p4[i].z;
                zl3 = reduce4(z[3]) + p4[i].w;
                float zs = c1 ? (c2 ? zl3 : zl1) : (c2 ? zl2 : zl0);
                float v  = fast_tanh(zs);
                gather16(v, sv);         // pure-VALU: no LDS round-trip
            }
            lds_fence();                 // p reads of this chunk consumed
            if (lane == 0) vf[2] = k + 1;
        }
        // ---- MLP head: y = relu(h1 @ W1^T + b1) @ W2^T + b2 ----
        if (c == 0) {
            float4 hf;
            hf.x = fast_tanh(zl0); hf.y = fast_tanh(zl1);
            hf.z = fast_tanh(zl2); hf.w = fast_tanh(zl3);
            *(float4*)&h1fin[4 * pos] = hf;
        }
        lds_fence();
        float r = 0.f;
        if (lane < 32) {
            float acc = b1[lane];
            const float* w1row = W1 + lane * HID;
            #pragma unroll
            for (int j = 0; j < HID; ++j) acc = fmaf(w1row[j], h1fin[j], acc);
            r = fmaxf(acc, 0.f) * W2[lane];
        }
        #pragma unroll
        for (int off = 32; off > 0; off >>= 1) r += __shfl_down(r, off);
        if (lane == 0) out[b] = r + b2[0];
    }
}

extern "C" void kernel_launch(void* const* d_in, const int* in_sizes, int n_in,
                              void* d_out, int out_size, void* d_ws, size_t ws_size,
                              hipStream_t stream)
{
    const int*   x    = (const int*)d_in[0];
    const float* emb  = (const float*)d_in[1];
    const float* Wih0 = (const float*)d_in[2];
    const float* Whh0 = (const float*)d_in[3];
    const float* bih0 = (const float*)d_in[4];
    const float* bhh0 = (const float*)d_in[5];
    const float* Wih1 = (const float*)d_in[6];
    const float* Whh1 = (const float*)d_in[7];
    const float* bih1 = (const float*)d_in[8];
    const float* bhh1 = (const float*)d_in[9];
    const float* W1   = (const float*)d_in[10];
    const float* b1   = (const float*)d_in[11];
    const float* W2   = (const float*)d_in[12];
    const float* b2   = (const float*)d_in[13];

    float* P0 = (float*)d_ws;   // 512*64*4 = 128 KiB scratch

    hipLaunchKernelGGL(p0_kernel, dim3(VOCAB), dim3(HID), 0, stream,
                       emb, Wih0, bih0, bhh0, P0);
    hipLaunchKernelGGL(rnn_kernel, dim3(BATCH), dim3(192), 0, stream,
                       x, P0, Whh0, Wih1, Whh1, bih1, bhh1,
                       W1, b1, W2, b2, (float*)d_out);
}